// Round 1
// 323.862 us; speedup vs baseline: 1.0143x; 1.0143x over previous
//
#include <hip/hip_runtime.h>
#include <hip/hip_bf16.h>

#define H 16
#define DM 1024
#define DK 64
#define B_ 4
#define N_ 2048

typedef __attribute__((ext_vector_type(8))) short bf16x8;
typedef __attribute__((ext_vector_type(4))) short s16x4;
typedef __attribute__((ext_vector_type(2))) unsigned int u32x2;
typedef __attribute__((ext_vector_type(4))) float f32x4;

static __device__ __forceinline__ short f2bs(float x) {
    __hip_bfloat16 b = __float2bfloat16(x);
    return *reinterpret_cast<short*>(&b);
}

// async 16B global -> LDS (LDS side is wave base + lane*16)
static __device__ __forceinline__ void async16(const void* g, void* l) {
    __builtin_amdgcn_global_load_lds(
        (const __attribute__((address_space(1))) void*)g,
        (__attribute__((address_space(3))) void*)l, 16, 0, 0);
}

// pack two fp32 -> two bf16 (truncation) in one v_perm_b32
static __device__ __forceinline__ unsigned packbf(float lo, float hi) {
    return __builtin_amdgcn_perm(__float_as_uint(hi), __float_as_uint(lo), 0x07060302u);
}

// ---------------------------------------------------------------------------
// Prep: y<3 -> fp32->bf16 convert of Q/K/V; y==3,x<1024 -> weight transposes
// ---------------------------------------------------------------------------
__global__ __launch_bounds__(256) void prep_kernel(
    const float* __restrict__ Q, const float* __restrict__ K, const float* __restrict__ V,
    const float* __restrict__ Wq, const float* __restrict__ Wk,
    const float* __restrict__ Wv, const float* __restrict__ Wo,
    short* __restrict__ Qb, short* __restrict__ Kb, short* __restrict__ Vb,
    short* __restrict__ wqT, short* __restrict__ wkT,
    short* __restrict__ wvT, short* __restrict__ woT)
{
    int y = blockIdx.y;
    if (y < 3) {
        const float* s = (y == 0) ? Q : (y == 1) ? K : V;
        short* d = (y == 0) ? Qb : (y == 1) ? Kb : Vb;
        size_t i = ((size_t)blockIdx.x * 256 + threadIdx.x) * 8;
        f32x4 a = *(const f32x4*)(s + i);
        f32x4 b = *(const f32x4*)(s + i + 4);
        bf16x8 p;
        #pragma unroll
        for (int j = 0; j < 4; ++j) { p[j] = f2bs(a[j]); p[4 + j] = f2bs(b[j]); }
        *(bf16x8*)(d + i) = p;
        return;
    }
    if (blockIdx.x >= 1024) return;
    __shared__ float tile[64][65];
    int z = blockIdx.x >> 8;
    int bx = blockIdx.x & 255;
    int t = threadIdx.x;
    int tj = t & 63, ti = t >> 6;

    if (z < 3) {
        const float* src = (z == 0) ? Wq : (z == 1) ? Wk : Wv;
        short* dst = (z == 0) ? wqT : (z == 1) ? wkT : wvT;
        int h = bx >> 4;
        int dmt = bx & 15;
        #pragma unroll
        for (int r = 0; r < 16; ++r) {
            int i = r * 4 + ti;
            tile[i][tj] = src[((size_t)h * 1024 + dmt * 64 + i) * 64 + tj];
        }
        __syncthreads();
        #pragma unroll
        for (int r = 0; r < 16; ++r) {
            int dk = r * 4 + ti;
            dst[((size_t)h * 64 + dk) * 1024 + dmt * 64 + tj] = f2bs(tile[tj][dk]);
        }
    } else {
        int kt = bx >> 4;
        int nt = bx & 15;
        #pragma unroll
        for (int r = 0; r < 16; ++r) {
            int i = r * 4 + ti;
            tile[i][tj] = Wo[((size_t)kt * 64 + i) * 1024 + nt * 64 + tj];
        }
        __syncthreads();
        #pragma unroll
        for (int r = 0; r < 16; ++r) {
            int jn = r * 4 + ti;
            woT[((size_t)nt * 64 + jn) * 1024 + kt * 64 + tj] = f2bs(tile[tj][jn]);
        }
    }
}

// ---------------------------------------------------------------------------
// GEMM mainloop, m97 structure: global_load_lds (width 16) direct to a single
// 16KB LDS buffer, 2 barriers per K-step. Staging map is pre-swizzled-global
// + linear-LDS (dst = wave_base + lane*16), which is exactly the HW rule for
// global_load_lds. Kills the VGPR round-trip + ds_write VALU of reg-staging.
// Tile 128x128, BK=32, 4 waves as 2x2 of 64x64. Multi-block TLP (16KB LDS ->
// ~6 blocks/CU) covers the barrier vmcnt drain (m97: 874-912 TF @128^2).
// ---------------------------------------------------------------------------
static __device__ __forceinline__ void gemm_mainloop(
    const short* __restrict__ A, const short* __restrict__ BT,
    int rowM0, int colN0, char* As, char* Bs, f32x4 (&acc)[4][4])
{
    int tid = threadIdx.x;
    int lane = tid & 63, w = tid >> 6;
    int l16 = lane & 15, quad = lane >> 4;
    int wm = w >> 1, wn = w & 1;
    int xg = (quad ^ ((l16 >> 1) & 3)) << 4;   // swizzled read slot

    // staging geometry: 8KB tile, rows of 64B (4 granules), XOR swizzle
    int r0 = w * 32 + (lane >> 2);
    int gsl = ((lane & 3) ^ ((lane >> 3) & 3)) << 4;
    int dst0 = w * 2048 + lane * 16;
    const char* Ag0 = (const char*)A + (size_t)(rowM0 + r0) * 2048 + gsl;
    const char* Ag1 = (const char*)A + (size_t)(rowM0 + r0 + 16) * 2048 + gsl;
    const char* Bg0 = (const char*)BT + (size_t)(colN0 + r0) * 2048 + gsl;
    const char* Bg1 = (const char*)BT + (size_t)(colN0 + r0 + 16) * 2048 + gsl;

    char* la0 = As + dst0;
    char* la1 = As + dst0 + 1024;
    char* lb0 = Bs + dst0;
    char* lb1 = Bs + dst0 + 1024;

    for (int it = 0; it < 32; ++it) {
        size_t kb = (size_t)it * 64;
        if (it) __syncthreads();               // prior frag reads complete
        async16(Ag0 + kb, la0);
        async16(Ag1 + kb, la1);
        async16(Bg0 + kb, lb0);
        async16(Bg1 + kb, lb1);
        __syncthreads();                       // vmcnt(0) drain -> tile published

        bf16x8 a[4], b[4];
        #pragma unroll
        for (int i = 0; i < 4; ++i)
            a[i] = *(const bf16x8*)(As + (wm * 64 + i * 16 + l16) * 64 + xg);
        #pragma unroll
        for (int j = 0; j < 4; ++j)
            b[j] = *(const bf16x8*)(Bs + (wn * 64 + j * 16 + l16) * 64 + xg);
        #pragma unroll
        for (int i = 0; i < 4; ++i)
            #pragma unroll
            for (int j = 0; j < 4; ++j)
                acc[i][j] = __builtin_amdgcn_mfma_f32_16x16x32_bf16(a[i], b[j], acc[i][j], 0, 0, 0);
    }
}

// ---------------------------------------------------------------------------
// Projections (q pre-scaled by 0.125*log2e)
// ---------------------------------------------------------------------------
__global__ __launch_bounds__(256) void proj_gemm(
    const short* __restrict__ Qb, const short* __restrict__ Kb, const short* __restrict__ Vb,
    const short* __restrict__ wqT, const short* __restrict__ wkT, const short* __restrict__ wvT,
    const float* __restrict__ bq, const float* __restrict__ bk, const float* __restrict__ bv,
    short* __restrict__ qbuf, short* __restrict__ kbuf, short* __restrict__ vTbuf)
{
    __shared__ char As[8192], Bs[8192];
    int which = blockIdx.z;
    const short* A  = (which == 0) ? Qb : (which == 1) ? Kb : Vb;
    const short* BT = (which == 0) ? wqT : (which == 1) ? wkT : wvT;
    const float* bias = (which == 0) ? bq : (which == 1) ? bk : bv;

    int rowM0 = blockIdx.x * 128;
    int colN0 = blockIdx.y * 128;

    f32x4 acc[4][4];
    #pragma unroll
    for (int i = 0; i < 4; ++i)
        #pragma unroll
        for (int j = 0; j < 4; ++j) acc[i][j] = (f32x4){0.f, 0.f, 0.f, 0.f};

    gemm_mainloop(A, BT, rowM0, colN0, As, Bs, acc);

    int lane = threadIdx.x & 63, w = threadIdx.x >> 6;
    int l16 = lane & 15, quad = lane >> 4;
    int wm = w >> 1, wn = w & 1;

    if (which == 2) {
        #pragma unroll
        for (int j = 0; j < 4; ++j) {
            int col = colN0 + wn * 64 + j * 16 + l16;
            int hh = col >> 6, dv = col & 63;
            float bs = bias[col];
            #pragma unroll
            for (int i = 0; i < 4; ++i) {
                int rowb = rowM0 + wm * 64 + i * 16 + quad * 4;
                int bb = rowb >> 11, n0 = rowb & 2047;
                s16x4 pk;
                #pragma unroll
                for (int r = 0; r < 4; ++r) pk[r] = f2bs(acc[i][j][r] + bs);
                *(s16x4*)(vTbuf + (((size_t)bb * H + hh) * DK + dv) * N_ + n0) = pk;
            }
        }
    } else {
        short* dst = (which == 0) ? qbuf : kbuf;
        float scl = (which == 0) ? 0.180336880f : 1.0f;   // 0.125 * log2(e)
        #pragma unroll
        for (int j = 0; j < 4; ++j) {
            int col = colN0 + wn * 64 + j * 16 + l16;
            float bs = bias[col];
            #pragma unroll
            for (int i = 0; i < 4; ++i) {
                int rowb = rowM0 + wm * 64 + i * 16 + quad * 4;
                #pragma unroll
                for (int r = 0; r < 4; ++r)
                    dst[(size_t)(rowb + r) * 1024 + col] = f2bs((acc[i][j][r] + bs) * scl);
            }
        }
    }
}

// ---------------------------------------------------------------------------
// Output projection
// ---------------------------------------------------------------------------
__global__ __launch_bounds__(256) void out_gemm(
    const short* __restrict__ obuf, const short* __restrict__ woT,
    const float* __restrict__ bo, float* __restrict__ out)
{
    __shared__ char As[8192], Bs[8192];
    int rowM0 = blockIdx.x * 128;
    int colN0 = blockIdx.y * 128;

    f32x4 acc[4][4];
    #pragma unroll
    for (int i = 0; i < 4; ++i)
        #pragma unroll
        for (int j = 0; j < 4; ++j) acc[i][j] = (f32x4){0.f, 0.f, 0.f, 0.f};

    gemm_mainloop(obuf, woT, rowM0, colN0, As, Bs, acc);

    int lane = threadIdx.x & 63, w = threadIdx.x >> 6;
    int l16 = lane & 15, quad = lane >> 4;
    int wm = w >> 1, wn = w & 1;

    #pragma unroll
    for (int j = 0; j < 4; ++j) {
        int col = colN0 + wn * 64 + j * 16 + l16;
        float bs = bo[col];
        #pragma unroll
        for (int i = 0; i < 4; ++i) {
            int rowb = rowM0 + wm * 64 + i * 16 + quad * 4;
            #pragma unroll
            for (int r = 0; r < 4; ++r)
                out[(size_t)(rowb + r) * 1024 + col] = acc[i][j][r] + bs;
        }
    }
}

// ---------------------------------------------------------------------------
// Flash attention (round 7): round-6 structure + T5 s_setprio(1) around the
// QK^T and PV MFMA clusters. Waves in a block run free between the staging
// barriers (no lockstep), so the CU scheduler has load-issuing vs MFMA-
// entering waves to arbitrate (m191: +4-7% on attention; GEMM-lockstep case
// is null so proj/out mainloop is left without setprio).
// ---------------------------------------------------------------------------
__global__ __launch_bounds__(256) void flash_kernel(
    const short* __restrict__ qbuf, const short* __restrict__ kbuf, const short* __restrict__ vT,
    short* __restrict__ obuf, const int* __restrict__ amask)
{
    __shared__ short Ks[2][4096];        // [key(perm)][dk] swizzled, dbuf
    __shared__ short Vs[2][4096];        // [dv][key] swizzled, dbuf
    __shared__ char  plds[4][2048];      // per-wave P tile 16x64, XOR-swizzled

    int bid = blockIdx.x;
    int g = bid & 7, idx = bid >> 3;
    int bh = g * 8 + (idx >> 4);         // XCD-affinity: one XCD -> 8 bh
    int xq = idx & 15;                   // q-tile pair selector
    int b = bh >> 4, h = bh & 15;

    int tid = threadIdx.x;
    int lane = tid & 63, wave = tid >> 6;
    int l16 = lane & 15, quad = lane >> 4;
    int msk = amask[0];

    int i8 = lane >> 3, i7 = lane & 7;
    int sg = (i7 ^ i8) << 4;
    int pk0 = i8 * 4 + wave;             // permuted K source row for LDS row wave*16+i8
    int skey = wave * 16 + i8;           // V source row (natural)
    int ldst = wave * 2048 + lane * 16;

    const char* kbase = (const char*)(kbuf + (size_t)b * 2048 * 1024 + h * 64);
    const char* vbase = (const char*)(vT + ((size_t)(b * 16 + h) * 64) * 2048);

    int m7 = l16 & 7;
    int g0 = (quad ^ m7) << 4;           // Ks/Vs read slots (row == l16 mod 8)
    int g1 = ((4 | quad) ^ m7) << 4;

    char* pw = plds[wave];
    int prd0 = l16 * 128 + g0;           // P A-frag reads (row = l16)
    int prd1 = l16 * 128 + g1;
    int pwa[4];                          // P write addrs (loop-invariant)
    #pragma unroll
    for (int r = 0; r < 4; ++r) {
        int row = quad * 4 + r;
        pwa[r] = row * 128 + (((l16 >> 1) ^ (row & 7)) << 4) + ((l16 & 1) << 3);
    }

    for (int pass = 0; pass < 2; ++pass) {
        int qt = pass ? (31 - xq) : xq;
        int qw = qt * 64 + wave * 16;
        int nkb = msk ? (qt + 1) : 32;

        const short* qp = qbuf + ((size_t)(b * 2048 + qw + l16)) * 1024 + h * 64;
        bf16x8 aq0 = *(const bf16x8*)(qp + quad * 8);
        bf16x8 aq1 = *(const bf16x8*)(qp + 32 + quad * 8);

        f32x4 o[4];
        float lsum[4];
        #pragma unroll
        for (int i = 0; i < 4; ++i) { o[i] = (f32x4){0.f, 0.f, 0.f, 0.f}; lsum[i] = 0.f; }

        // stage tile 0 into buffer 0
        async16(kbase + (size_t)pk0 * 2048 + sg, (char*)Ks[0] + ldst);
        async16(kbase + (size_t)(pk0 + 32) * 2048 + sg, (char*)Ks[0] + ldst + 1024);
        async16(vbase + (size_t)skey * 4096 + sg, (char*)Vs[0] + ldst);
        async16(vbase + (size_t)(skey + 8) * 4096 + sg, (char*)Vs[0] + ldst + 1024);

        for (int ib = 0; ib < nkb; ++ib) {
            __syncthreads();             // publishes buf[ib&1]
            int cur = ib & 1;
            if (ib + 1 < nkb) {
                int nb = (ib + 1) & 1;
                size_t kb2 = (size_t)(ib + 1) * 64;
                async16(kbase + (kb2 + pk0) * 2048 + sg, (char*)Ks[nb] + ldst);
                async16(kbase + (kb2 + pk0 + 32) * 2048 + sg, (char*)Ks[nb] + ldst + 1024);
                async16(vbase + (size_t)skey * 4096 + kb2 * 2 + sg, (char*)Vs[nb] + ldst);
                async16(vbase + (size_t)(skey + 8) * 4096 + kb2 * 2 + sg, (char*)Vs[nb] + ldst + 1024);
            }
            int kb = ib * 64;

            // S = q K^T (log2 domain; S column (nt,l16) = key 4*l16+nt)
            f32x4 s[4];
            __builtin_amdgcn_s_setprio(1);
            #pragma unroll
            for (int nt = 0; nt < 4; ++nt) {
                const char* kr = (const char*)Ks[cur] + (nt * 16 + l16) * 128;
                bf16x8 b0 = *(const bf16x8*)(kr + g0);
                bf16x8 b1 = *(const bf16x8*)(kr + g1);
                f32x4 t = (f32x4){0.f, 0.f, 0.f, 0.f};
                t = __builtin_amdgcn_mfma_f32_16x16x32_bf16(aq0, b0, t, 0, 0, 0);
                t = __builtin_amdgcn_mfma_f32_16x16x32_bf16(aq1, b1, t, 0, 0, 0);
                s[nt] = t;
            }
            __builtin_amdgcn_s_setprio(0);

            if (msk && (kb + 63 > qw)) {
                #pragma unroll
                for (int r = 0; r < 4; ++r) {
                    int row = qw + quad * 4 + r;
                    #pragma unroll
                    for (int nt = 0; nt < 4; ++nt) {
                        int col = kb + l16 * 4 + nt;
                        if (col > row) s[nt][r] = -3e38f;
                    }
                }
            }

            // p = exp2(s); truncation-pack to bf16 via v_perm; defer row sums
            __builtin_amdgcn_wave_barrier();
            #pragma unroll
            for (int r = 0; r < 4; ++r) {
                float p0 = __builtin_amdgcn_exp2f(s[0][r]);
                float p1 = __builtin_amdgcn_exp2f(s[1][r]);
                float p2 = __builtin_amdgcn_exp2f(s[2][r]);
                float p3 = __builtin_amdgcn_exp2f(s[3][r]);
                lsum[r] += (p0 + p1) + (p2 + p3);
                u32x2 pk;
                pk[0] = packbf(p0, p1);
                pk[1] = packbf(p2, p3);
                *(u32x2*)(pw + pwa[r]) = pk;
            }
            __builtin_amdgcn_wave_barrier();
            bf16x8 ap0 = *(const bf16x8*)(pw + prd0);
            bf16x8 ap1 = *(const bf16x8*)(pw + prd1);
            __builtin_amdgcn_wave_barrier();

            // O += P V (natural key order on both sides)
            __builtin_amdgcn_s_setprio(1);
            #pragma unroll
            for (int vb = 0; vb < 4; ++vb) {
                const char* vr = (const char*)Vs[cur] + (vb * 16 + l16) * 128;
                bf16x8 v0 = *(const bf16x8*)(vr + g0);
                bf16x8 v1 = *(const bf16x8*)(vr + g1);
                o[vb] = __builtin_amdgcn_mfma_f32_16x16x32_bf16(ap0, v0, o[vb], 0, 0, 0);
                o[vb] = __builtin_amdgcn_mfma_f32_16x16x32_bf16(ap1, v1, o[vb], 0, 0, 0);
            }
            __builtin_amdgcn_s_setprio(0);
        }

        // epilogue: reduce row sums across 16 col-lanes, normalize, store
        #pragma unroll
        for (int r = 0; r < 4; ++r) {
            float t = lsum[r];
            #pragma unroll
            for (int off = 1; off < 16; off <<= 1) t += __shfl_xor(t, off, 64);
            float inv = 1.0f / t;
            int row = qw + quad * 4 + r;
            #pragma unroll
            for (int vb = 0; vb < 4; ++vb)
                obuf[((size_t)(b * 2048 + row)) * 1024 + h * 64 + vb * 16 + l16] =
                    f2bs(o[vb][r] * inv);
        }
        __syncthreads();   // pass boundary: K/V buffers safe to restage
    }
}

// ---------------------------------------------------------------------------
extern "C" void kernel_launch(void* const* d_in, const int* in_sizes, int n_in,
                              void* d_out, int out_size, void* d_ws, size_t ws_size,
                              hipStream_t stream)
{
    const float* Q  = (const float*)d_in[0];
    const float* K  = (const float*)d_in[1];
    const float* V  = (const float*)d_in[2];
    const float* Wq = (const float*)d_in[3];
    const float* bq = (const float*)d_in[4];
    const float* Wk = (const float*)d_in[5];
    const float* bk = (const float*)d_in[6];
    const float* Wv = (const float*)d_in[7];
    const float* bv = (const float*)d_in[8];
    const float* Wo = (const float*)d_in[9];
    const float* bo = (const float*)d_in[10];
    const int* amask = (const int*)d_in[11];
    float* out = (float*)d_out;

    char* ws = (char*)d_ws;
    const size_t SZ = (size_t)B_ * N_ * DM * sizeof(short);      // 16 MiB each
    const size_t SZW = (size_t)H * DK * DM * sizeof(short);      // 2 MiB each
    short* Qb    = (short*)ws; ws += SZ;       // reused as obuf after proj
    short* Kb    = (short*)ws; ws += SZ;
    short* Vb    = (short*)ws; ws += SZ;
    short* qbuf  = (short*)ws; ws += SZ;
    short* kbuf  = (short*)ws; ws += SZ;
    short* vTbuf = (short*)ws; ws += SZ;
    short* wqT   = (short*)ws; ws += SZW;
    short* wkT   = (short*)ws; ws += SZW;
    short* wvT   = (short*)ws; ws += SZW;
    short* woT   = (short*)ws; ws += SZW;
    short* obuf  = Qb;

    prep_kernel<<<dim3(4096, 4), dim3(256), 0, stream>>>(Q, K, V, Wq, Wk, Wv, Wo,
                                                         Qb, Kb, Vb, wqT, wkT, wvT, woT);
    proj_gemm<<<dim3(64, 8, 3), dim3(256), 0, stream>>>(Qb, Kb, Vb, wqT, wkT, wvT,
                                                        bq, bk, bv, qbuf, kbuf, vTbuf);
    flash_kernel<<<dim3(1024), dim3(256), 0, stream>>>(qbuf, kbuf, vTbuf, obuf, amask);
    out_gemm<<<dim3(64, 8), dim3(256), 0, stream>>>(obuf, woT, bo, out);
}

// Round 2
// 310.348 us; speedup vs baseline: 1.0585x; 1.0435x over previous
//
#include <hip/hip_runtime.h>
#include <hip/hip_bf16.h>

#define H 16
#define DM 1024
#define DK 64
#define B_ 4
#define N_ 2048

typedef __attribute__((ext_vector_type(8))) short bf16x8;
typedef __attribute__((ext_vector_type(4))) short s16x4;
typedef __attribute__((ext_vector_type(2))) unsigned int u32x2;
typedef __attribute__((ext_vector_type(4))) float f32x4;

static __device__ __forceinline__ short f2bs(float x) {
    __hip_bfloat16 b = __float2bfloat16(x);
    return *reinterpret_cast<short*>(&b);
}

// async 16B global -> LDS (LDS side is wave base + lane*16)
static __device__ __forceinline__ void async16(const void* g, void* l) {
    __builtin_amdgcn_global_load_lds(
        (const __attribute__((address_space(1))) void*)g,
        (__attribute__((address_space(3))) void*)l, 16, 0, 0);
}

// pack two fp32 -> two bf16 (truncation) in one v_perm_b32
static __device__ __forceinline__ unsigned packbf(float lo, float hi) {
    return __builtin_amdgcn_perm(__float_as_uint(hi), __float_as_uint(lo), 0x07060302u);
}

// ---------------------------------------------------------------------------
// Prep: y<3 -> fp32->bf16 convert of Q/K/V; y==3,x<1024 -> weight transposes
// ---------------------------------------------------------------------------
__global__ __launch_bounds__(256) void prep_kernel(
    const float* __restrict__ Q, const float* __restrict__ K, const float* __restrict__ V,
    const float* __restrict__ Wq, const float* __restrict__ Wk,
    const float* __restrict__ Wv, const float* __restrict__ Wo,
    short* __restrict__ Qb, short* __restrict__ Kb, short* __restrict__ Vb,
    short* __restrict__ wqT, short* __restrict__ wkT,
    short* __restrict__ wvT, short* __restrict__ woT)
{
    int y = blockIdx.y;
    if (y < 3) {
        const float* s = (y == 0) ? Q : (y == 1) ? K : V;
        short* d = (y == 0) ? Qb : (y == 1) ? Kb : Vb;
        size_t i = ((size_t)blockIdx.x * 256 + threadIdx.x) * 8;
        f32x4 a = *(const f32x4*)(s + i);
        f32x4 b = *(const f32x4*)(s + i + 4);
        bf16x8 p;
        #pragma unroll
        for (int j = 0; j < 4; ++j) { p[j] = f2bs(a[j]); p[4 + j] = f2bs(b[j]); }
        *(bf16x8*)(d + i) = p;
        return;
    }
    if (blockIdx.x >= 1024) return;
    __shared__ float tile[64][65];
    int z = blockIdx.x >> 8;
    int bx = blockIdx.x & 255;
    int t = threadIdx.x;
    int tj = t & 63, ti = t >> 6;

    if (z < 3) {
        const float* src = (z == 0) ? Wq : (z == 1) ? Wk : Wv;
        short* dst = (z == 0) ? wqT : (z == 1) ? wkT : wvT;
        int h = bx >> 4;
        int dmt = bx & 15;
        #pragma unroll
        for (int r = 0; r < 16; ++r) {
            int i = r * 4 + ti;
            tile[i][tj] = src[((size_t)h * 1024 + dmt * 64 + i) * 64 + tj];
        }
        __syncthreads();
        #pragma unroll
        for (int r = 0; r < 16; ++r) {
            int dk = r * 4 + ti;
            dst[((size_t)h * 64 + dk) * 1024 + dmt * 64 + tj] = f2bs(tile[tj][dk]);
        }
    } else {
        int kt = bx >> 4;
        int nt = bx & 15;
        #pragma unroll
        for (int r = 0; r < 16; ++r) {
            int i = r * 4 + ti;
            tile[i][tj] = Wo[((size_t)kt * 64 + i) * 1024 + nt * 64 + tj];
        }
        __syncthreads();
        #pragma unroll
        for (int r = 0; r < 16; ++r) {
            int jn = r * 4 + ti;
            woT[((size_t)nt * 64 + jn) * 1024 + kt * 64 + tj] = f2bs(tile[tj][jn]);
        }
    }
}

// ---------------------------------------------------------------------------
// GEMM mainloop, counted-vmcnt pipeline (T3/T4 minimum form):
// triple-buffered LDS (3 x 16KB), global_load_lds issued 2 tiles ahead,
// raw s_barrier (no implicit vmcnt(0) drain) + asm s_waitcnt vmcnt(8) --
// never 0 in steady state. The oldest tile's 4 loads are waited while 8
// newer stay in flight ACROSS the barriers; ~2 iterations of in-wave
// hiding covers the ~900-cyc HBM miss latency that the __syncthreads()
// version exposed every K-step (measured: 1000 cyc/step, 638 TF).
// Tile 128x128, BK=32, 4 waves as 2x2 of 64x64.
// ---------------------------------------------------------------------------
static __device__ __forceinline__ void gemm_mainloop(
    const short* __restrict__ A, const short* __restrict__ BT,
    int rowM0, int colN0, char* lds, f32x4 (&acc)[4][4])
{
    int tid = threadIdx.x;
    int lane = tid & 63, w = tid >> 6;
    int l16 = lane & 15, quad = lane >> 4;
    int wm = w >> 1, wn = w & 1;
    int xg = (quad ^ ((l16 >> 1) & 3)) << 4;   // swizzled read slot

    // staging geometry: 8KB tile, rows of 64B (4 granules), XOR swizzle
    int r0 = w * 32 + (lane >> 2);
    int gsl = ((lane & 3) ^ ((lane >> 3) & 3)) << 4;
    int dst0 = w * 2048 + lane * 16;
    const char* Ag0 = (const char*)A + (size_t)(rowM0 + r0) * 2048 + gsl;
    const char* Ag1 = Ag0 + 16 * 2048;
    const char* Bg0 = (const char*)BT + (size_t)(colN0 + r0) * 2048 + gsl;
    const char* Bg1 = Bg0 + 16 * 2048;

    // prologue: tiles 0,1,2 into bufs 0,1,2 (buf: A at +0, B at +8192)
    #pragma unroll
    for (int t = 0; t < 3; ++t) {
        size_t kb = (size_t)t * 64;
        char* As = lds + t * 16384;
        char* Bs = As + 8192;
        async16(Ag0 + kb, As + dst0);
        async16(Ag1 + kb, As + dst0 + 1024);
        async16(Bg0 + kb, Bs + dst0);
        async16(Bg1 + kb, Bs + dst0 + 1024);
    }

    int c0 = 0;                                // rotating buffer byte offset
    for (int it = 0; it < 32; ++it) {
        // wait: oldest in-flight tile (it) landed; 8 newer ops stay in flight
        if (it < 30)       asm volatile("s_waitcnt vmcnt(8)" ::: "memory");
        else if (it == 30) asm volatile("s_waitcnt vmcnt(4)" ::: "memory");
        else               asm volatile("s_waitcnt vmcnt(0)" ::: "memory");
        __builtin_amdgcn_s_barrier();          // publish tile it (no drain)
        asm volatile("" ::: "memory");
        __builtin_amdgcn_sched_barrier(0);

        const char* As = lds + c0;
        const char* Bs = As + 8192;
        bf16x8 a[4], b[4];
        #pragma unroll
        for (int i = 0; i < 4; ++i)
            a[i] = *(const bf16x8*)(As + (wm * 64 + i * 16 + l16) * 64 + xg);
        #pragma unroll
        for (int j = 0; j < 4; ++j)
            b[j] = *(const bf16x8*)(Bs + (wn * 64 + j * 16 + l16) * 64 + xg);
        #pragma unroll
        for (int i = 0; i < 4; ++i)
            #pragma unroll
            for (int j = 0; j < 4; ++j)
                acc[i][j] = __builtin_amdgcn_mfma_f32_16x16x32_bf16(a[i], b[j], acc[i][j], 0, 0, 0);

        asm volatile("" ::: "memory");
        __builtin_amdgcn_s_barrier();          // all waves done reading buf c0
        __builtin_amdgcn_sched_barrier(0);
        if (it + 3 < 32) {                     // refill buf c0 with tile it+3
            size_t kb = (size_t)(it + 3) * 64;
            char* Aw = lds + c0;
            char* Bw = Aw + 8192;
            async16(Ag0 + kb, Aw + dst0);
            async16(Ag1 + kb, Aw + dst0 + 1024);
            async16(Bg0 + kb, Bw + dst0);
            async16(Bg1 + kb, Bw + dst0 + 1024);
        }
        c0 += 16384;
        if (c0 == 49152) c0 = 0;
    }
}

// ---------------------------------------------------------------------------
// Projections (q pre-scaled by 0.125*log2e)
// ---------------------------------------------------------------------------
__global__ __launch_bounds__(256) void proj_gemm(
    const short* __restrict__ Qb, const short* __restrict__ Kb, const short* __restrict__ Vb,
    const short* __restrict__ wqT, const short* __restrict__ wkT, const short* __restrict__ wvT,
    const float* __restrict__ bq, const float* __restrict__ bk, const float* __restrict__ bv,
    short* __restrict__ qbuf, short* __restrict__ kbuf, short* __restrict__ vTbuf)
{
    __shared__ char lds[49152];
    int which = blockIdx.z;
    const short* A  = (which == 0) ? Qb : (which == 1) ? Kb : Vb;
    const short* BT = (which == 0) ? wqT : (which == 1) ? wkT : wvT;
    const float* bias = (which == 0) ? bq : (which == 1) ? bk : bv;

    int rowM0 = blockIdx.x * 128;
    int colN0 = blockIdx.y * 128;

    f32x4 acc[4][4];
    #pragma unroll
    for (int i = 0; i < 4; ++i)
        #pragma unroll
        for (int j = 0; j < 4; ++j) acc[i][j] = (f32x4){0.f, 0.f, 0.f, 0.f};

    gemm_mainloop(A, BT, rowM0, colN0, lds, acc);

    int lane = threadIdx.x & 63, w = threadIdx.x >> 6;
    int l16 = lane & 15, quad = lane >> 4;
    int wm = w >> 1, wn = w & 1;

    if (which == 2) {
        #pragma unroll
        for (int j = 0; j < 4; ++j) {
            int col = colN0 + wn * 64 + j * 16 + l16;
            int hh = col >> 6, dv = col & 63;
            float bs = bias[col];
            #pragma unroll
            for (int i = 0; i < 4; ++i) {
                int rowb = rowM0 + wm * 64 + i * 16 + quad * 4;
                int bb = rowb >> 11, n0 = rowb & 2047;
                s16x4 pk;
                #pragma unroll
                for (int r = 0; r < 4; ++r) pk[r] = f2bs(acc[i][j][r] + bs);
                *(s16x4*)(vTbuf + (((size_t)bb * H + hh) * DK + dv) * N_ + n0) = pk;
            }
        }
    } else {
        short* dst = (which == 0) ? qbuf : kbuf;
        float scl = (which == 0) ? 0.180336880f : 1.0f;   // 0.125 * log2(e)
        #pragma unroll
        for (int j = 0; j < 4; ++j) {
            int col = colN0 + wn * 64 + j * 16 + l16;
            float bs = bias[col];
            #pragma unroll
            for (int i = 0; i < 4; ++i) {
                int rowb = rowM0 + wm * 64 + i * 16 + quad * 4;
                #pragma unroll
                for (int r = 0; r < 4; ++r)
                    dst[(size_t)(rowb + r) * 1024 + col] = f2bs((acc[i][j][r] + bs) * scl);
            }
        }
    }
}

// ---------------------------------------------------------------------------
// Output projection
// ---------------------------------------------------------------------------
__global__ __launch_bounds__(256) void out_gemm(
    const short* __restrict__ obuf, const short* __restrict__ woT,
    const float* __restrict__ bo, float* __restrict__ out)
{
    __shared__ char lds[49152];
    int rowM0 = blockIdx.x * 128;
    int colN0 = blockIdx.y * 128;

    f32x4 acc[4][4];
    #pragma unroll
    for (int i = 0; i < 4; ++i)
        #pragma unroll
        for (int j = 0; j < 4; ++j) acc[i][j] = (f32x4){0.f, 0.f, 0.f, 0.f};

    gemm_mainloop(obuf, woT, rowM0, colN0, lds, acc);

    int lane = threadIdx.x & 63, w = threadIdx.x >> 6;
    int l16 = lane & 15, quad = lane >> 4;
    int wm = w >> 1, wn = w & 1;

    #pragma unroll
    for (int j = 0; j < 4; ++j) {
        int col = colN0 + wn * 64 + j * 16 + l16;
        float bs = bo[col];
        #pragma unroll
        for (int i = 0; i < 4; ++i) {
            int rowb = rowM0 + wm * 64 + i * 16 + quad * 4;
            #pragma unroll
            for (int r = 0; r < 4; ++r)
                out[(size_t)(rowb + r) * 1024 + col] = acc[i][j][r] + bs;
        }
    }
}

// ---------------------------------------------------------------------------
// Flash attention (round 7 structure, unchanged this round):
// setprio(1) around QK^T and PV MFMA clusters.
// ---------------------------------------------------------------------------
__global__ __launch_bounds__(256) void flash_kernel(
    const short* __restrict__ qbuf, const short* __restrict__ kbuf, const short* __restrict__ vT,
    short* __restrict__ obuf, const int* __restrict__ amask)
{
    __shared__ short Ks[2][4096];        // [key(perm)][dk] swizzled, dbuf
    __shared__ short Vs[2][4096];        // [dv][key] swizzled, dbuf
    __shared__ char  plds[4][2048];      // per-wave P tile 16x64, XOR-swizzled

    int bid = blockIdx.x;
    int g = bid & 7, idx = bid >> 3;
    int bh = g * 8 + (idx >> 4);         // XCD-affinity: one XCD -> 8 bh
    int xq = idx & 15;                   // q-tile pair selector
    int b = bh >> 4, h = bh & 15;

    int tid = threadIdx.x;
    int lane = tid & 63, wave = tid >> 6;
    int l16 = lane & 15, quad = lane >> 4;
    int msk = amask[0];

    int i8 = lane >> 3, i7 = lane & 7;
    int sg = (i7 ^ i8) << 4;
    int pk0 = i8 * 4 + wave;             // permuted K source row for LDS row wave*16+i8
    int skey = wave * 16 + i8;           // V source row (natural)
    int ldst = wave * 2048 + lane * 16;

    const char* kbase = (const char*)(kbuf + (size_t)b * 2048 * 1024 + h * 64);
    const char* vbase = (const char*)(vT + ((size_t)(b * 16 + h) * 64) * 2048);

    int m7 = l16 & 7;
    int g0 = (quad ^ m7) << 4;           // Ks/Vs read slots (row == l16 mod 8)
    int g1 = ((4 | quad) ^ m7) << 4;

    char* pw = plds[wave];
    int prd0 = l16 * 128 + g0;           // P A-frag reads (row = l16)
    int prd1 = l16 * 128 + g1;
    int pwa[4];                          // P write addrs (loop-invariant)
    #pragma unroll
    for (int r = 0; r < 4; ++r) {
        int row = quad * 4 + r;
        pwa[r] = row * 128 + (((l16 >> 1) ^ (row & 7)) << 4) + ((l16 & 1) << 3);
    }

    for (int pass = 0; pass < 2; ++pass) {
        int qt = pass ? (31 - xq) : xq;
        int qw = qt * 64 + wave * 16;
        int nkb = msk ? (qt + 1) : 32;

        const short* qp = qbuf + ((size_t)(b * 2048 + qw + l16)) * 1024 + h * 64;
        bf16x8 aq0 = *(const bf16x8*)(qp + quad * 8);
        bf16x8 aq1 = *(const bf16x8*)(qp + 32 + quad * 8);

        f32x4 o[4];
        float lsum[4];
        #pragma unroll
        for (int i = 0; i < 4; ++i) { o[i] = (f32x4){0.f, 0.f, 0.f, 0.f}; lsum[i] = 0.f; }

        // stage tile 0 into buffer 0
        async16(kbase + (size_t)pk0 * 2048 + sg, (char*)Ks[0] + ldst);
        async16(kbase + (size_t)(pk0 + 32) * 2048 + sg, (char*)Ks[0] + ldst + 1024);
        async16(vbase + (size_t)skey * 4096 + sg, (char*)Vs[0] + ldst);
        async16(vbase + (size_t)(skey + 8) * 4096 + sg, (char*)Vs[0] + ldst + 1024);

        for (int ib = 0; ib < nkb; ++ib) {
            __syncthreads();             // publishes buf[ib&1]
            int cur = ib & 1;
            if (ib + 1 < nkb) {
                int nb = (ib + 1) & 1;
                size_t kb2 = (size_t)(ib + 1) * 64;
                async16(kbase + (kb2 + pk0) * 2048 + sg, (char*)Ks[nb] + ldst);
                async16(kbase + (kb2 + pk0 + 32) * 2048 + sg, (char*)Ks[nb] + ldst + 1024);
                async16(vbase + (size_t)skey * 4096 + kb2 * 2 + sg, (char*)Vs[nb] + ldst);
                async16(vbase + (size_t)(skey + 8) * 4096 + kb2 * 2 + sg, (char*)Vs[nb] + ldst + 1024);
            }
            int kb = ib * 64;

            // S = q K^T (log2 domain; S column (nt,l16) = key 4*l16+nt)
            f32x4 s[4];
            __builtin_amdgcn_s_setprio(1);
            #pragma unroll
            for (int nt = 0; nt < 4; ++nt) {
                const char* kr = (const char*)Ks[cur] + (nt * 16 + l16) * 128;
                bf16x8 b0 = *(const bf16x8*)(kr + g0);
                bf16x8 b1 = *(const bf16x8*)(kr + g1);
                f32x4 t = (f32x4){0.f, 0.f, 0.f, 0.f};
                t = __builtin_amdgcn_mfma_f32_16x16x32_bf16(aq0, b0, t, 0, 0, 0);
                t = __builtin_amdgcn_mfma_f32_16x16x32_bf16(aq1, b1, t, 0, 0, 0);
                s[nt] = t;
            }
            __builtin_amdgcn_s_setprio(0);

            if (msk && (kb + 63 > qw)) {
                #pragma unroll
                for (int r = 0; r < 4; ++r) {
                    int row = qw + quad * 4 + r;
                    #pragma unroll
                    for (int nt = 0; nt < 4; ++nt) {
                        int col = kb + l16 * 4 + nt;
                        if (col > row) s[nt][r] = -3e38f;
                    }
                }
            }

            // p = exp2(s); truncation-pack to bf16 via v_perm; defer row sums
            __builtin_amdgcn_wave_barrier();
            #pragma unroll
            for (int r = 0; r < 4; ++r) {
                float p0 = __builtin_amdgcn_exp2f(s[0][r]);
                float p1 = __builtin_amdgcn_exp2f(s[1][r]);
                float p2 = __builtin_amdgcn_exp2f(s[2][r]);
                float p3 = __builtin_amdgcn_exp2f(s[3][r]);
                lsum[r] += (p0 + p1) + (p2 + p3);
                u32x2 pk;
                pk[0] = packbf(p0, p1);
                pk[1] = packbf(p2, p3);
                *(u32x2*)(pw + pwa[r]) = pk;
            }
            __builtin_amdgcn_wave_barrier();
            bf16x8 ap0 = *(const bf16x8*)(pw + prd0);
            bf16x8 ap1 = *(const bf16x8*)(pw + prd1);
            __builtin_amdgcn_wave_barrier();

            // O += P V (natural key order on both sides)
            __builtin_amdgcn_s_setprio(1);
            #pragma unroll
            for (int vb = 0; vb < 4; ++vb) {
                const char* vr = (const char*)Vs[cur] + (vb * 16 + l16) * 128;
                bf16x8 v0 = *(const bf16x8*)(vr + g0);
                bf16x8 v1 = *(const bf16x8*)(vr + g1);
                o[vb] = __builtin_amdgcn_mfma_f32_16x16x32_bf16(ap0, v0, o[vb], 0, 0, 0);
                o[vb] = __builtin_amdgcn_mfma_f32_16x16x32_bf16(ap1, v1, o[vb], 0, 0, 0);
            }
            __builtin_amdgcn_s_setprio(0);
        }

        // epilogue: reduce row sums across 16 col-lanes, normalize, store
        #pragma unroll
        for (int r = 0; r < 4; ++r) {
            float t = lsum[r];
            #pragma unroll
            for (int off = 1; off < 16; off <<= 1) t += __shfl_xor(t, off, 64);
            float inv = 1.0f / t;
            int row = qw + quad * 4 + r;
            #pragma unroll
            for (int vb = 0; vb < 4; ++vb)
                obuf[((size_t)(b * 2048 + row)) * 1024 + h * 64 + vb * 16 + l16] =
                    f2bs(o[vb][r] * inv);
        }
        __syncthreads();   // pass boundary: K/V buffers safe to restage
    }
}

// ---------------------------------------------------------------------------
extern "C" void kernel_launch(void* const* d_in, const int* in_sizes, int n_in,
                              void* d_out, int out_size, void* d_ws, size_t ws_size,
                              hipStream_t stream)
{
    const float* Q  = (const float*)d_in[0];
    const float* K  = (const float*)d_in[1];
    const float* V  = (const float*)d_in[2];
    const float* Wq = (const float*)d_in[3];
    const float* bq = (const float*)d_in[4];
    const float* Wk = (const float*)d_in[5];
    const float* bk = (const float*)d_in[6];
    const float* Wv = (const float*)d_in[7];
    const float* bv = (const float*)d_in[8];
    const float* Wo = (const float*)d_in[9];
    const float* bo = (const float*)d_in[10];
    const int* amask = (const int*)d_in[11];
    float* out = (float*)d_out;

    char* ws = (char*)d_ws;
    const size_t SZ = (size_t)B_ * N_ * DM * sizeof(short);      // 16 MiB each
    const size_t SZW = (size_t)H * DK * DM * sizeof(short);      // 2 MiB each
    short* Qb    = (short*)ws; ws += SZ;       // reused as obuf after proj
    short* Kb    = (short*)ws; ws += SZ;
    short* Vb    = (short*)ws; ws += SZ;
    short* qbuf  = (short*)ws; ws += SZ;
    short* kbuf  = (short*)ws; ws += SZ;
    short* vTbuf = (short*)ws; ws += SZ;
    short* wqT   = (short*)ws; ws += SZW;
    short* wkT   = (short*)ws; ws += SZW;
    short* wvT   = (short*)ws; ws += SZW;
    short* woT   = (short*)ws; ws += SZW;
    short* obuf  = Qb;

    prep_kernel<<<dim3(4096, 4), dim3(256), 0, stream>>>(Q, K, V, Wq, Wk, Wv, Wo,
                                                         Qb, Kb, Vb, wqT, wkT, wvT, woT);
    proj_gemm<<<dim3(64, 8, 3), dim3(256), 0, stream>>>(Qb, Kb, Vb, wqT, wkT, wvT,
                                                        bq, bk, bv, qbuf, kbuf, vTbuf);
    flash_kernel<<<dim3(1024), dim3(256), 0, stream>>>(qbuf, kbuf, vTbuf, obuf, amask);
    out_gemm<<<dim3(64, 8), dim3(256), 0, stream>>>(obuf, woT, bo, out);
}

// Round 3
// 303.256 us; speedup vs baseline: 1.0832x; 1.0234x over previous
//
#include <hip/hip_runtime.h>
#include <hip/hip_bf16.h>

#define H 16
#define DM 1024
#define DK 64
#define B_ 4
#define N_ 2048

typedef __attribute__((ext_vector_type(8))) short bf16x8;
typedef __attribute__((ext_vector_type(4))) short s16x4;
typedef __attribute__((ext_vector_type(2))) unsigned int u32x2;
typedef __attribute__((ext_vector_type(4))) float f32x4;

static __device__ __forceinline__ short f2bs(float x) {
    __hip_bfloat16 b = __float2bfloat16(x);
    return *reinterpret_cast<short*>(&b);
}

// async 16B global -> LDS (LDS side is wave base + lane*16)
static __device__ __forceinline__ void async16(const void* g, void* l) {
    __builtin_amdgcn_global_load_lds(
        (const __attribute__((address_space(1))) void*)g,
        (__attribute__((address_space(3))) void*)l, 16, 0, 0);
}

// pack two fp32 -> two bf16 (truncation) in one v_perm_b32
static __device__ __forceinline__ unsigned packbf(float lo, float hi) {
    return __builtin_amdgcn_perm(__float_as_uint(hi), __float_as_uint(lo), 0x07060302u);
}

// ---------------------------------------------------------------------------
// Prep: y<3 -> fp32->bf16 convert of Q/K/V; y==3,x<1024 -> weight transposes
// ---------------------------------------------------------------------------
__global__ __launch_bounds__(256) void prep_kernel(
    const float* __restrict__ Q, const float* __restrict__ K, const float* __restrict__ V,
    const float* __restrict__ Wq, const float* __restrict__ Wk,
    const float* __restrict__ Wv, const float* __restrict__ Wo,
    short* __restrict__ Qb, short* __restrict__ Kb, short* __restrict__ Vb,
    short* __restrict__ wqT, short* __restrict__ wkT,
    short* __restrict__ wvT, short* __restrict__ woT)
{
    int y = blockIdx.y;
    if (y < 3) {
        const float* s = (y == 0) ? Q : (y == 1) ? K : V;
        short* d = (y == 0) ? Qb : (y == 1) ? Kb : Vb;
        size_t i = ((size_t)blockIdx.x * 256 + threadIdx.x) * 8;
        f32x4 a = *(const f32x4*)(s + i);
        f32x4 b = *(const f32x4*)(s + i + 4);
        bf16x8 p;
        #pragma unroll
        for (int j = 0; j < 4; ++j) { p[j] = f2bs(a[j]); p[4 + j] = f2bs(b[j]); }
        *(bf16x8*)(d + i) = p;
        return;
    }
    if (blockIdx.x >= 1024) return;
    __shared__ float tile[64][65];
    int z = blockIdx.x >> 8;
    int bx = blockIdx.x & 255;
    int t = threadIdx.x;
    int tj = t & 63, ti = t >> 6;

    if (z < 3) {
        const float* src = (z == 0) ? Wq : (z == 1) ? Wk : Wv;
        short* dst = (z == 0) ? wqT : (z == 1) ? wkT : wvT;
        int h = bx >> 4;
        int dmt = bx & 15;
        #pragma unroll
        for (int r = 0; r < 16; ++r) {
            int i = r * 4 + ti;
            tile[i][tj] = src[((size_t)h * 1024 + dmt * 64 + i) * 64 + tj];
        }
        __syncthreads();
        #pragma unroll
        for (int r = 0; r < 16; ++r) {
            int dk = r * 4 + ti;
            dst[((size_t)h * 64 + dk) * 1024 + dmt * 64 + tj] = f2bs(tile[tj][dk]);
        }
    } else {
        int kt = bx >> 4;
        int nt = bx & 15;
        #pragma unroll
        for (int r = 0; r < 16; ++r) {
            int i = r * 4 + ti;
            tile[i][tj] = Wo[((size_t)kt * 64 + i) * 1024 + nt * 64 + tj];
        }
        __syncthreads();
        #pragma unroll
        for (int r = 0; r < 16; ++r) {
            int jn = r * 4 + ti;
            woT[((size_t)nt * 64 + jn) * 1024 + kt * 64 + tj] = f2bs(tile[tj][jn]);
        }
    }
}

// ---------------------------------------------------------------------------
// GEMM mainloop: counted-vmcnt pipeline, ONE barrier per K-step.
// 3 x 16KB rotating LDS bufs. Per step t:
//   s_waitcnt vmcnt(4)   (own tile-t loads landed; tile t+1 stays in flight)
//   s_barrier            (broadcasts: ALL waves' tile-t loads landed; also
//                         proves everyone drained step t-1's ds_reads, since
//                         a wave only reaches this barrier after lgkmcnt(0)
//                         before its step t-1 MFMAs)
//   refill tile t+2 into buf (t+2)%3 == (t-1)%3  (safe by the above)
//   ds_read + MFMA on buf t%3
// Steady-state vmcnt is 4 -- never drained to 0 until the last step (T4).
// Tile 128x128, BK=32, 4 waves as 2x2 of 64x64.
// ---------------------------------------------------------------------------
static __device__ __forceinline__ void gemm_mainloop(
    const short* __restrict__ A, const short* __restrict__ BT,
    int rowM0, int colN0, char* lds, f32x4 (&acc)[4][4])
{
    int tid = threadIdx.x;
    int lane = tid & 63, w = tid >> 6;
    int l16 = lane & 15, quad = lane >> 4;
    int wm = w >> 1, wn = w & 1;
    int xg = (quad ^ ((l16 >> 1) & 3)) << 4;   // swizzled read slot

    // staging geometry: 8KB tile, rows of 64B (4 granules), XOR swizzle
    int r0 = w * 32 + (lane >> 2);
    int gsl = ((lane & 3) ^ ((lane >> 3) & 3)) << 4;
    int dst0 = w * 2048 + lane * 16;
    const char* Ag0 = (const char*)A + (size_t)(rowM0 + r0) * 2048 + gsl;
    const char* Ag1 = Ag0 + 16 * 2048;
    const char* Bg0 = (const char*)BT + (size_t)(colN0 + r0) * 2048 + gsl;
    const char* Bg1 = Bg0 + 16 * 2048;

    // prologue: tiles 0,1 into bufs 0,1 (buf: A at +0, B at +8192)
    #pragma unroll
    for (int t = 0; t < 2; ++t) {
        size_t kb = (size_t)t * 64;
        char* As = lds + t * 16384;
        char* Bs = As + 8192;
        async16(Ag0 + kb, As + dst0);
        async16(Ag1 + kb, As + dst0 + 1024);
        async16(Bg0 + kb, Bs + dst0);
        async16(Bg1 + kb, Bs + dst0 + 1024);
    }

    int c0 = 0;          // consume buf offset (tile t)
    int cr = 32768;      // refill buf offset (tile t+2)
    for (int it = 0; it < 32; ++it) {
        if (it < 31) asm volatile("s_waitcnt vmcnt(4)" ::: "memory");
        else         asm volatile("s_waitcnt vmcnt(0)" ::: "memory");
        __builtin_amdgcn_s_barrier();
        __builtin_amdgcn_sched_barrier(0);

        if (it + 2 < 32) {                     // refill freed buffer
            size_t kb = (size_t)(it + 2) * 64;
            char* Aw = lds + cr;
            char* Bw = Aw + 8192;
            async16(Ag0 + kb, Aw + dst0);
            async16(Ag1 + kb, Aw + dst0 + 1024);
            async16(Bg0 + kb, Bw + dst0);
            async16(Bg1 + kb, Bw + dst0 + 1024);
        }
        __builtin_amdgcn_sched_barrier(0);

        const char* As = lds + c0;
        const char* Bs = As + 8192;
        bf16x8 a[4], b[4];
        #pragma unroll
        for (int i = 0; i < 4; ++i)
            a[i] = *(const bf16x8*)(As + (wm * 64 + i * 16 + l16) * 64 + xg);
        #pragma unroll
        for (int j = 0; j < 4; ++j)
            b[j] = *(const bf16x8*)(Bs + (wn * 64 + j * 16 + l16) * 64 + xg);
        #pragma unroll
        for (int i = 0; i < 4; ++i)
            #pragma unroll
            for (int j = 0; j < 4; ++j)
                acc[i][j] = __builtin_amdgcn_mfma_f32_16x16x32_bf16(a[i], b[j], acc[i][j], 0, 0, 0);

        c0 += 16384; if (c0 == 49152) c0 = 0;
        cr += 16384; if (cr == 49152) cr = 0;
    }
}

// ---------------------------------------------------------------------------
// Projections (q pre-scaled by 0.125*log2e).
// Grid is 1D (1536) with XCD-affinity encoding: id = ((which*64 + rhigh*8 +
// col) << 3) | xcd, row = rhigh*8 + xcd. The 8 col-blocks sharing one A
// row-panel are consecutive on ONE XCD and step through the same K-slices
// concurrently -> A re-reads hit that XCD's L2 instead of pulling ~768 MB
// through L3 (measured 21 TB/s aggregate staging traffic was the limiter).
// ---------------------------------------------------------------------------
__global__ __launch_bounds__(256) void proj_gemm(
    const short* __restrict__ Qb, const short* __restrict__ Kb, const short* __restrict__ Vb,
    const short* __restrict__ wqT, const short* __restrict__ wkT, const short* __restrict__ wvT,
    const float* __restrict__ bq, const float* __restrict__ bk, const float* __restrict__ bv,
    short* __restrict__ qbuf, short* __restrict__ kbuf, short* __restrict__ vTbuf)
{
    __shared__ char lds[49152];
    int id = blockIdx.x;
    int xcd = id & 7;
    int k = id >> 3;                 // 0..191
    int which = k >> 6;              // 0..2
    int rem = k & 63;
    int r = ((rem >> 3) << 3) | xcd; // row-tile 0..63, row%8 == xcd
    int c = rem & 7;                 // col-tile 0..7

    const short* A  = (which == 0) ? Qb : (which == 1) ? Kb : Vb;
    const short* BT = (which == 0) ? wqT : (which == 1) ? wkT : wvT;
    const float* bias = (which == 0) ? bq : (which == 1) ? bk : bv;

    int rowM0 = r * 128;
    int colN0 = c * 128;

    f32x4 acc[4][4];
    #pragma unroll
    for (int i = 0; i < 4; ++i)
        #pragma unroll
        for (int j = 0; j < 4; ++j) acc[i][j] = (f32x4){0.f, 0.f, 0.f, 0.f};

    gemm_mainloop(A, BT, rowM0, colN0, lds, acc);

    int lane = threadIdx.x & 63, w = threadIdx.x >> 6;
    int l16 = lane & 15, quad = lane >> 4;
    int wm = w >> 1, wn = w & 1;

    if (which == 2) {
        #pragma unroll
        for (int j = 0; j < 4; ++j) {
            int col = colN0 + wn * 64 + j * 16 + l16;
            int hh = col >> 6, dv = col & 63;
            float bs = bias[col];
            #pragma unroll
            for (int i = 0; i < 4; ++i) {
                int rowb = rowM0 + wm * 64 + i * 16 + quad * 4;
                int bb = rowb >> 11, n0 = rowb & 2047;
                s16x4 pk;
                #pragma unroll
                for (int r2 = 0; r2 < 4; ++r2) pk[r2] = f2bs(acc[i][j][r2] + bs);
                *(s16x4*)(vTbuf + (((size_t)bb * H + hh) * DK + dv) * N_ + n0) = pk;
            }
        }
    } else {
        short* dst = (which == 0) ? qbuf : kbuf;
        float scl = (which == 0) ? 0.180336880f : 1.0f;   // 0.125 * log2(e)
        #pragma unroll
        for (int j = 0; j < 4; ++j) {
            int col = colN0 + wn * 64 + j * 16 + l16;
            float bs = bias[col];
            #pragma unroll
            for (int i = 0; i < 4; ++i) {
                int rowb = rowM0 + wm * 64 + i * 16 + quad * 4;
                #pragma unroll
                for (int r2 = 0; r2 < 4; ++r2)
                    dst[(size_t)(rowb + r2) * 1024 + col] = f2bs((acc[i][j][r2] + bs) * scl);
            }
        }
    }
}

// ---------------------------------------------------------------------------
// Output projection (same XCD-affinity 1D grid, 512 blocks)
// ---------------------------------------------------------------------------
__global__ __launch_bounds__(256) void out_gemm(
    const short* __restrict__ obuf, const short* __restrict__ woT,
    const float* __restrict__ bo, float* __restrict__ out)
{
    __shared__ char lds[49152];
    int id = blockIdx.x;
    int xcd = id & 7;
    int k = id >> 3;                 // 0..63
    int r = ((k >> 3) << 3) | xcd;   // row-tile 0..63
    int c = k & 7;                   // col-tile 0..7

    int rowM0 = r * 128;
    int colN0 = c * 128;

    f32x4 acc[4][4];
    #pragma unroll
    for (int i = 0; i < 4; ++i)
        #pragma unroll
        for (int j = 0; j < 4; ++j) acc[i][j] = (f32x4){0.f, 0.f, 0.f, 0.f};

    gemm_mainloop(obuf, woT, rowM0, colN0, lds, acc);

    int lane = threadIdx.x & 63, w = threadIdx.x >> 6;
    int l16 = lane & 15, quad = lane >> 4;
    int wm = w >> 1, wn = w & 1;

    #pragma unroll
    for (int j = 0; j < 4; ++j) {
        int col = colN0 + wn * 64 + j * 16 + l16;
        float bs = bo[col];
        #pragma unroll
        for (int i = 0; i < 4; ++i) {
            int rowb = rowM0 + wm * 64 + i * 16 + quad * 4;
            #pragma unroll
            for (int r2 = 0; r2 < 4; ++r2)
                out[(size_t)(rowb + r2) * 1024 + col] = acc[i][j][r2] + bs;
        }
    }
}

// ---------------------------------------------------------------------------
// Flash attention (unchanged this round):
// setprio(1) around QK^T and PV MFMA clusters.
// ---------------------------------------------------------------------------
__global__ __launch_bounds__(256) void flash_kernel(
    const short* __restrict__ qbuf, const short* __restrict__ kbuf, const short* __restrict__ vT,
    short* __restrict__ obuf, const int* __restrict__ amask)
{
    __shared__ short Ks[2][4096];        // [key(perm)][dk] swizzled, dbuf
    __shared__ short Vs[2][4096];        // [dv][key] swizzled, dbuf
    __shared__ char  plds[4][2048];      // per-wave P tile 16x64, XOR-swizzled

    int bid = blockIdx.x;
    int g = bid & 7, idx = bid >> 3;
    int bh = g * 8 + (idx >> 4);         // XCD-affinity: one XCD -> 8 bh
    int xq = idx & 15;                   // q-tile pair selector
    int b = bh >> 4, h = bh & 15;

    int tid = threadIdx.x;
    int lane = tid & 63, wave = tid >> 6;
    int l16 = lane & 15, quad = lane >> 4;
    int msk = amask[0];

    int i8 = lane >> 3, i7 = lane & 7;
    int sg = (i7 ^ i8) << 4;
    int pk0 = i8 * 4 + wave;             // permuted K source row for LDS row wave*16+i8
    int skey = wave * 16 + i8;           // V source row (natural)
    int ldst = wave * 2048 + lane * 16;

    const char* kbase = (const char*)(kbuf + (size_t)b * 2048 * 1024 + h * 64);
    const char* vbase = (const char*)(vT + ((size_t)(b * 16 + h) * 64) * 2048);

    int m7 = l16 & 7;
    int g0 = (quad ^ m7) << 4;           // Ks/Vs read slots (row == l16 mod 8)
    int g1 = ((4 | quad) ^ m7) << 4;

    char* pw = plds[wave];
    int prd0 = l16 * 128 + g0;           // P A-frag reads (row = l16)
    int prd1 = l16 * 128 + g1;
    int pwa[4];                          // P write addrs (loop-invariant)
    #pragma unroll
    for (int r = 0; r < 4; ++r) {
        int row = quad * 4 + r;
        pwa[r] = row * 128 + (((l16 >> 1) ^ (row & 7)) << 4) + ((l16 & 1) << 3);
    }

    for (int pass = 0; pass < 2; ++pass) {
        int qt = pass ? (31 - xq) : xq;
        int qw = qt * 64 + wave * 16;
        int nkb = msk ? (qt + 1) : 32;

        const short* qp = qbuf + ((size_t)(b * 2048 + qw + l16)) * 1024 + h * 64;
        bf16x8 aq0 = *(const bf16x8*)(qp + quad * 8);
        bf16x8 aq1 = *(const bf16x8*)(qp + 32 + quad * 8);

        f32x4 o[4];
        float lsum[4];
        #pragma unroll
        for (int i = 0; i < 4; ++i) { o[i] = (f32x4){0.f, 0.f, 0.f, 0.f}; lsum[i] = 0.f; }

        // stage tile 0 into buffer 0
        async16(kbase + (size_t)pk0 * 2048 + sg, (char*)Ks[0] + ldst);
        async16(kbase + (size_t)(pk0 + 32) * 2048 + sg, (char*)Ks[0] + ldst + 1024);
        async16(vbase + (size_t)skey * 4096 + sg, (char*)Vs[0] + ldst);
        async16(vbase + (size_t)(skey + 8) * 4096 + sg, (char*)Vs[0] + ldst + 1024);

        for (int ib = 0; ib < nkb; ++ib) {
            __syncthreads();             // publishes buf[ib&1]
            int cur = ib & 1;
            if (ib + 1 < nkb) {
                int nb = (ib + 1) & 1;
                size_t kb2 = (size_t)(ib + 1) * 64;
                async16(kbase + (kb2 + pk0) * 2048 + sg, (char*)Ks[nb] + ldst);
                async16(kbase + (kb2 + pk0 + 32) * 2048 + sg, (char*)Ks[nb] + ldst + 1024);
                async16(vbase + (size_t)skey * 4096 + kb2 * 2 + sg, (char*)Vs[nb] + ldst);
                async16(vbase + (size_t)(skey + 8) * 4096 + kb2 * 2 + sg, (char*)Vs[nb] + ldst + 1024);
            }
            int kb = ib * 64;

            // S = q K^T (log2 domain; S column (nt,l16) = key 4*l16+nt)
            f32x4 s[4];
            __builtin_amdgcn_s_setprio(1);
            #pragma unroll
            for (int nt = 0; nt < 4; ++nt) {
                const char* kr = (const char*)Ks[cur] + (nt * 16 + l16) * 128;
                bf16x8 b0 = *(const bf16x8*)(kr + g0);
                bf16x8 b1 = *(const bf16x8*)(kr + g1);
                f32x4 t = (f32x4){0.f, 0.f, 0.f, 0.f};
                t = __builtin_amdgcn_mfma_f32_16x16x32_bf16(aq0, b0, t, 0, 0, 0);
                t = __builtin_amdgcn_mfma_f32_16x16x32_bf16(aq1, b1, t, 0, 0, 0);
                s[nt] = t;
            }
            __builtin_amdgcn_s_setprio(0);

            if (msk && (kb + 63 > qw)) {
                #pragma unroll
                for (int r = 0; r < 4; ++r) {
                    int row = qw + quad * 4 + r;
                    #pragma unroll
                    for (int nt = 0; nt < 4; ++nt) {
                        int col = kb + l16 * 4 + nt;
                        if (col > row) s[nt][r] = -3e38f;
                    }
                }
            }

            // p = exp2(s); truncation-pack to bf16 via v_perm; defer row sums
            __builtin_amdgcn_wave_barrier();
            #pragma unroll
            for (int r = 0; r < 4; ++r) {
                float p0 = __builtin_amdgcn_exp2f(s[0][r]);
                float p1 = __builtin_amdgcn_exp2f(s[1][r]);
                float p2 = __builtin_amdgcn_exp2f(s[2][r]);
                float p3 = __builtin_amdgcn_exp2f(s[3][r]);
                lsum[r] += (p0 + p1) + (p2 + p3);
                u32x2 pk;
                pk[0] = packbf(p0, p1);
                pk[1] = packbf(p2, p3);
                *(u32x2*)(pw + pwa[r]) = pk;
            }
            __builtin_amdgcn_wave_barrier();
            bf16x8 ap0 = *(const bf16x8*)(pw + prd0);
            bf16x8 ap1 = *(const bf16x8*)(pw + prd1);
            __builtin_amdgcn_wave_barrier();

            // O += P V (natural key order on both sides)
            __builtin_amdgcn_s_setprio(1);
            #pragma unroll
            for (int vb = 0; vb < 4; ++vb) {
                const char* vr = (const char*)Vs[cur] + (vb * 16 + l16) * 128;
                bf16x8 v0 = *(const bf16x8*)(vr + g0);
                bf16x8 v1 = *(const bf16x8*)(vr + g1);
                o[vb] = __builtin_amdgcn_mfma_f32_16x16x32_bf16(ap0, v0, o[vb], 0, 0, 0);
                o[vb] = __builtin_amdgcn_mfma_f32_16x16x32_bf16(ap1, v1, o[vb], 0, 0, 0);
            }
            __builtin_amdgcn_s_setprio(0);
        }

        // epilogue: reduce row sums across 16 col-lanes, normalize, store
        #pragma unroll
        for (int r = 0; r < 4; ++r) {
            float t = lsum[r];
            #pragma unroll
            for (int off = 1; off < 16; off <<= 1) t += __shfl_xor(t, off, 64);
            float inv = 1.0f / t;
            int row = qw + quad * 4 + r;
            #pragma unroll
            for (int vb = 0; vb < 4; ++vb)
                obuf[((size_t)(b * 2048 + row)) * 1024 + h * 64 + vb * 16 + l16] =
                    f2bs(o[vb][r] * inv);
        }
        __syncthreads();   // pass boundary: K/V buffers safe to restage
    }
}

// ---------------------------------------------------------------------------
extern "C" void kernel_launch(void* const* d_in, const int* in_sizes, int n_in,
                              void* d_out, int out_size, void* d_ws, size_t ws_size,
                              hipStream_t stream)
{
    const float* Q  = (const float*)d_in[0];
    const float* K  = (const float*)d_in[1];
    const float* V  = (const float*)d_in[2];
    const float* Wq = (const float*)d_in[3];
    const float* bq = (const float*)d_in[4];
    const float* Wk = (const float*)d_in[5];
    const float* bk = (const float*)d_in[6];
    const float* Wv = (const float*)d_in[7];
    const float* bv = (const float*)d_in[8];
    const float* Wo = (const float*)d_in[9];
    const float* bo = (const float*)d_in[10];
    const int* amask = (const int*)d_in[11];
    float* out = (float*)d_out;

    char* ws = (char*)d_ws;
    const size_t SZ = (size_t)B_ * N_ * DM * sizeof(short);      // 16 MiB each
    const size_t SZW = (size_t)H * DK * DM * sizeof(short);      // 2 MiB each
    short* Qb    = (short*)ws; ws += SZ;       // reused as obuf after proj
    short* Kb    = (short*)ws; ws += SZ;
    short* Vb    = (short*)ws; ws += SZ;
    short* qbuf  = (short*)ws; ws += SZ;
    short* kbuf  = (short*)ws; ws += SZ;
    short* vTbuf = (short*)ws; ws += SZ;
    short* wqT   = (short*)ws; ws += SZW;
    short* wkT   = (short*)ws; ws += SZW;
    short* wvT   = (short*)ws; ws += SZW;
    short* woT   = (short*)ws; ws += SZW;
    short* obuf  = Qb;

    prep_kernel<<<dim3(4096, 4), dim3(256), 0, stream>>>(Q, K, V, Wq, Wk, Wv, Wo,
                                                         Qb, Kb, Vb, wqT, wkT, wvT, woT);
    proj_gemm<<<dim3(1536), dim3(256), 0, stream>>>(Qb, Kb, Vb, wqT, wkT, wvT,
                                                    bq, bk, bv, qbuf, kbuf, vTbuf);
    flash_kernel<<<dim3(1024), dim3(256), 0, stream>>>(qbuf, kbuf, vTbuf, obuf, amask);
    out_gemm<<<dim3(512), dim3(256), 0, stream>>>(obuf, woT, bo, out);
}